// Round 1
// 2115.607 us; speedup vs baseline: 1.0046x; 1.0046x over previous
//
#include <hip/hip_runtime.h>

#define N_USERS 1000000
#define NEDGE   32000000
#define OUT_F   64
#define BN_EPS  1e-5f

// Destination binning geometry
#define SBITS     10
#define S_BUCKET  1024                     // nodes per bucket
#define NB        977                      // ceil(N_USERS / S_BUCKET)
#define CAP       36864                    // per-bucket record capacity (mean 32768 + 22 sigma)
#define SCAT_BLOCKS 2048                   // was 512: grid was the occupancy limiter (2 blk/CU)
#define CHUNK     (NEDGE / SCAT_BLOCKS)    // 15625
#define SPLIT     4                        // blocks per bucket in the hop kernel

// ---------------- binned path ----------------

__global__ void init_cursors(unsigned* __restrict__ cursors) {
    int i = blockIdx.x * blockDim.x + threadIdx.x;
    if (i < NB) cursors[i] = (unsigned)i * CAP;
}

// Partition edges by destination bucket. Per block: LDS histogram of its chunk,
// one global atomicAdd per non-empty bucket to reserve a contiguous range, then
// scatter packed 8B records (meta = dst_local<<20 | src, weight bits).
__global__ __launch_bounds__(256) void scatter_bin(
    const int* __restrict__ src, const int* __restrict__ dst,
    const float* __restrict__ ew, uint2* __restrict__ rec,
    unsigned* __restrict__ cursors) {
    __shared__ unsigned cnt[NB];
    __shared__ unsigned base[NB];
    int tid = threadIdx.x;
    int start = blockIdx.x * CHUNK;
    int end = start + CHUNK;

    for (int i = tid; i < NB; i += 256) cnt[i] = 0;
    __syncthreads();
    for (int i = start + tid; i < end; i += 256)
        atomicAdd(&cnt[dst[i] >> SBITS], 1u);
    __syncthreads();
    for (int i = tid; i < NB; i += 256) {
        unsigned c = cnt[i];
        base[i] = c ? atomicAdd(&cursors[i], c) : 0u;
    }
    __syncthreads();
    for (int i = tid; i < NB; i += 256) cnt[i] = 0;
    __syncthreads();
    for (int i = start + tid; i < end; i += 256) {
        int d = dst[i];
        int b = d >> SBITS;
        unsigned p = base[b] + atomicAdd(&cnt[b], 1u);
        unsigned meta = ((unsigned)(d & (S_BUCKET - 1)) << 20) | (unsigned)src[i];
        rec[p] = make_uint2(meta, __float_as_uint(ew[i]));
    }
}

// SPLIT blocks per destination bucket: each accumulates a slice of the bucket's
// records into a 4KB LDS array (ds_add_f32), then one coalesced global
// atomicAdd flush. uint4 loads process 2 records/iter for memory-level
// parallelism on the random cur[] gathers.
__global__ __launch_bounds__(256) void hop_bucket_split(
    const uint2* __restrict__ rec, const unsigned* __restrict__ cursors,
    const float* __restrict__ cur, float* __restrict__ nxt) {
    __shared__ float acc[S_BUCKET];
    int tid = threadIdx.x;
    int b = blockIdx.x / SPLIT;
    int s = blockIdx.x % SPLIT;
    for (int i = tid; i < S_BUCKET; i += 256) acc[i] = 0.0f;
    __syncthreads();

    unsigned start = (unsigned)b * CAP;          // 16B-aligned (CAP even)
    unsigned cnt = cursors[b] - start;           // records in this bucket
    unsigned u0 = ((cnt * (unsigned)s) / SPLIT) & ~1u;
    unsigned u1 = (s == SPLIT - 1) ? cnt : (((cnt * (unsigned)(s + 1)) / SPLIT) & ~1u);
    const uint2* bptr = rec + start;

    for (unsigned i = u0 + 2u * (unsigned)tid; i < u1; i += 512u) {
        if (i + 1u < u1) {
            uint4 r = *(const uint4*)(bptr + i);   // 2 records, 16B aligned (i even)
            float m0 = cur[r.x & 0xFFFFFu] * __uint_as_float(r.y);
            float m1 = cur[r.z & 0xFFFFFu] * __uint_as_float(r.w);
            atomicAdd(&acc[r.x >> 20], m0);
            atomicAdd(&acc[r.z >> 20], m1);
        } else {
            uint2 r = bptr[i];
            atomicAdd(&acc[r.x >> 20], cur[r.x & 0xFFFFFu] * __uint_as_float(r.y));
        }
    }
    __syncthreads();

    int nb0 = b << SBITS;
    for (int i = tid; i < S_BUCKET; i += 256) {
        int n = nb0 + i;
        if (n < N_USERS) atomicAdd(&nxt[n], acc[i]);
    }
}

// ---------------- fallback path (round-1, device atomics) ----------------

__global__ void zero_kernel(float* __restrict__ p, int n) {
    int i = blockIdx.x * blockDim.x + threadIdx.x;
    int stride = gridDim.x * blockDim.x;
    for (; i < n; i += stride) p[i] = 0.0f;
}

__global__ __launch_bounds__(256) void hop_atomic(
    const int* __restrict__ src, const int* __restrict__ dst,
    const float* __restrict__ ew, const float* __restrict__ cur,
    float* __restrict__ nxt) {
    int e = blockIdx.x * blockDim.x + threadIdx.x;
    if (e * 4 < NEDGE) {
        int4   s = ((const int4*)src)[e];
        int4   d = ((const int4*)dst)[e];
        float4 w = ((const float4*)ew)[e];
        atomicAdd(&nxt[d.x], cur[s.x] * w.x);
        atomicAdd(&nxt[d.y], cur[s.y] * w.y);
        atomicAdd(&nxt[d.z], cur[s.z] * w.z);
        atomicAdd(&nxt[d.w], cur[s.w] * w.w);
    }
}

// ---------------- finalize: 5->64 matvec + BatchNorm over features ----------------

__global__ __launch_bounds__(256) void finalize_kernel(
    const float* __restrict__ x,  const float* __restrict__ f1,
    const float* __restrict__ f2, const float* __restrict__ f3,
    const float* __restrict__ f4, const float* __restrict__ W,
    const float* __restrict__ bias, const float* __restrict__ gamma,
    const float* __restrict__ beta, float* __restrict__ out) {
    int lane = threadIdx.x & 63;
    int waveInBlock = threadIdx.x >> 6;
    int wavesPerBlock = blockDim.x >> 6;
    int gwave  = blockIdx.x * wavesPerBlock + waveInBlock;
    int nwaves = gridDim.x * wavesPerBlock;

    float w0 = W[lane * 5 + 0];
    float w1 = W[lane * 5 + 1];
    float w2 = W[lane * 5 + 2];
    float w3 = W[lane * 5 + 3];
    float w4 = W[lane * 5 + 4];
    float b  = bias[lane];

    for (int n = gwave; n < N_USERS; n += nwaves) {
        float c0 = x[n], c1 = f1[n], c2 = f2[n], c3 = f3[n], c4 = f4[n];
        float y = b + c0 * w0 + c1 * w1 + c2 * w2 + c3 * w3 + c4 * w4;

        float s = y;
        #pragma unroll
        for (int off = 32; off; off >>= 1) s += __shfl_xor(s, off);
        float mean = s * (1.0f / 64.0f);

        float d = y - mean;
        float v = d * d;
        #pragma unroll
        for (int off = 32; off; off >>= 1) v += __shfl_xor(v, off);
        float var = v * (1.0f / 64.0f);

        float o = d * rsqrtf(var + BN_EPS) * gamma[n] + beta[n];
        out[(size_t)n * OUT_F + lane] = o;
    }
}

extern "C" void kernel_launch(void* const* d_in, const int* in_sizes, int n_in,
                              void* d_out, int out_size, void* d_ws, size_t ws_size,
                              hipStream_t stream) {
    const float* x     = (const float*)d_in[0];
    const int*   ei    = (const int*)d_in[1];
    const float* ew    = (const float*)d_in[2];
    const float* W     = (const float*)d_in[3];
    const float* bias  = (const float*)d_in[4];
    const float* gamma = (const float*)d_in[5];
    const float* beta  = (const float*)d_in[6];
    float* out = (float*)d_out;

    const int* src = ei;
    const int* dst = ei + NEDGE;

    // Workspace layout
    float* f = (float*)d_ws;                           // 4*N floats (16 MB)
    uint2* rec = (uint2*)(f + 4ull * N_USERS);         // NB*CAP records (288 MB)
    unsigned* cursors = (unsigned*)(rec + (size_t)NB * CAP);
    size_t needed = 4ull * N_USERS * 4 + (size_t)NB * CAP * 8 + (size_t)NB * 4;

    if (ws_size >= needed) {
        init_cursors<<<(NB + 255) / 256, 256, 0, stream>>>(cursors);
        zero_kernel<<<2048, 256, 0, stream>>>(f, 4 * N_USERS);   // hop flush is atomicAdd now
        scatter_bin<<<SCAT_BLOCKS, 256, 0, stream>>>(src, dst, ew, rec, cursors);
        const float* cur = x;
        for (int h = 0; h < 4; ++h) {
            float* nxt = f + (size_t)h * N_USERS;
            hop_bucket_split<<<NB * SPLIT, 256, 0, stream>>>(rec, cursors, cur, nxt);
            cur = nxt;
        }
    } else {
        zero_kernel<<<4096, 256, 0, stream>>>(f, 4 * N_USERS);
        const float* cur = x;
        for (int h = 0; h < 4; ++h) {
            float* nxt = f + (size_t)h * N_USERS;
            hop_atomic<<<NEDGE / 4 / 256, 256, 0, stream>>>(src, dst, ew, cur, nxt);
            cur = nxt;
        }
    }

    finalize_kernel<<<2048, 256, 0, stream>>>(
        x, f, f + N_USERS, f + 2 * N_USERS, f + 3 * N_USERS,
        W, bias, gamma, beta, out);
}

// Round 3
// 1917.042 us; speedup vs baseline: 1.1087x; 1.1036x over previous
//
#include <hip/hip_runtime.h>

#define N_USERS 1000000
#define NEDGE   32000000
#define OUT_F   64
#define BN_EPS  1e-5f

// Destination binning geometry.
// S_BUCKET=4096 is the max where meta packs: dst_local(12b)<<20 | src(20b).
// NB=245 keeps the scatter write-combine set (resident_blocks * NB * 64B ~ 16MB)
// inside L2 so record lines fill completely before eviction (round-1: NB=977
// gave 3.7x write amplification, 947MB written for 256MB of records).
#define SBITS     12
#define S_BUCKET  4096                     // nodes per bucket
#define NB        245                      // ceil(N_USERS / S_BUCKET)
#define CAP       139264                   // per-bucket capacity: mean 130612 + 24 sigma, mult of 4
#define SCAT_BLOCKS 1024
#define CHUNK     (NEDGE / SCAT_BLOCKS)    // 31250
#define SPLIT     8                        // blocks per bucket in the hop kernel

typedef unsigned int uint4v __attribute__((ext_vector_type(4)));  // nontemporal-loadable

// ---------------- binned path ----------------

__global__ void init_cursors(unsigned* __restrict__ cursors) {
    int i = blockIdx.x * blockDim.x + threadIdx.x;
    if (i < NB) cursors[i] = (unsigned)i * CAP;
}

// Partition edges by destination bucket. Per block: LDS histogram of its chunk,
// one global atomicAdd per non-empty bucket to reserve a contiguous range, then
// scatter packed 8B records (meta = dst_local<<20 | src, weight bits).
// Input streams are nontemporal so they don't evict the partially-filled
// record lines from L2.
__global__ __launch_bounds__(256) void scatter_bin(
    const int* __restrict__ src, const int* __restrict__ dst,
    const float* __restrict__ ew, uint2* __restrict__ rec,
    unsigned* __restrict__ cursors) {
    __shared__ unsigned cnt[NB];
    __shared__ unsigned base[NB];
    int tid = threadIdx.x;
    int start = blockIdx.x * CHUNK;
    int end = start + CHUNK;

    for (int i = tid; i < NB; i += 256) cnt[i] = 0;
    __syncthreads();
    for (int i = start + tid; i < end; i += 256) {
        int d = __builtin_nontemporal_load(&dst[i]);
        atomicAdd(&cnt[d >> SBITS], 1u);
    }
    __syncthreads();
    for (int i = tid; i < NB; i += 256) {
        unsigned c = cnt[i];
        base[i] = c ? atomicAdd(&cursors[i], c) : 0u;
    }
    __syncthreads();
    for (int i = tid; i < NB; i += 256) cnt[i] = 0;
    __syncthreads();
    for (int i = start + tid; i < end; i += 256) {
        int d = __builtin_nontemporal_load(&dst[i]);
        int s = __builtin_nontemporal_load(&src[i]);
        float w = __builtin_nontemporal_load(&ew[i]);
        int b = d >> SBITS;
        unsigned p = base[b] + atomicAdd(&cnt[b], 1u);
        unsigned meta = ((unsigned)(d & (S_BUCKET - 1)) << 20) | (unsigned)s;
        rec[p] = make_uint2(meta, __float_as_uint(w));
    }
}

// SPLIT blocks per destination bucket: each accumulates a slice of the bucket's
// records into a 16KB LDS array (ds_add_f32), then one coalesced global
// atomicAdd flush. 4 records/iter (two aligned 16B nontemporal loads) keep
// 4 independent gathers in flight; nt on the rec stream preserves the 4MB
// cur[] array in per-XCD L2 so gathers hit L2 instead of L3.
__global__ __launch_bounds__(256) void hop_bucket_split(
    const uint2* __restrict__ rec, const unsigned* __restrict__ cursors,
    const float* __restrict__ cur, float* __restrict__ nxt) {
    __shared__ float acc[S_BUCKET];
    int tid = threadIdx.x;
    int b = blockIdx.x / SPLIT;
    int s = blockIdx.x % SPLIT;
    for (int i = tid; i < S_BUCKET; i += 256) acc[i] = 0.0f;
    __syncthreads();

    unsigned start = (unsigned)b * CAP;          // 32B-aligned (CAP mult of 4)
    unsigned cnt = cursors[b] - start;           // records in this bucket
    unsigned u0 = ((cnt * (unsigned)s) / SPLIT) & ~3u;
    unsigned u1 = (s == SPLIT - 1) ? cnt : (((cnt * (unsigned)(s + 1)) / SPLIT) & ~3u);
    const uint2* bptr = rec + start;

    unsigned i = u0 + 4u * (unsigned)tid;
    for (; i + 4u <= u1; i += 4u * 256u) {
        uint4v r0 = __builtin_nontemporal_load(reinterpret_cast<const uint4v*>(bptr + i));
        uint4v r1 = __builtin_nontemporal_load(reinterpret_cast<const uint4v*>(bptr + i + 2));
        float c0 = cur[r0.x & 0xFFFFFu];
        float c1 = cur[r0.z & 0xFFFFFu];
        float c2 = cur[r1.x & 0xFFFFFu];
        float c3 = cur[r1.z & 0xFFFFFu];
        atomicAdd(&acc[r0.x >> 20], c0 * __uint_as_float(r0.y));
        atomicAdd(&acc[r0.z >> 20], c1 * __uint_as_float(r0.w));
        atomicAdd(&acc[r1.x >> 20], c2 * __uint_as_float(r1.y));
        atomicAdd(&acc[r1.z >> 20], c3 * __uint_as_float(r1.w));
    }
    if (i < u1) {                                // at most one straddling quad per bucket-slice
        for (unsigned j = i; j < i + 4u && j < u1; ++j) {
            uint2 r = bptr[j];
            atomicAdd(&acc[r.x >> 20], cur[r.x & 0xFFFFFu] * __uint_as_float(r.y));
        }
    }
    __syncthreads();

    int nb0 = b << SBITS;
    for (int k = tid; k < S_BUCKET; k += 256) {
        int n = nb0 + k;
        if (n < N_USERS) atomicAdd(&nxt[n], acc[k]);
    }
}

// ---------------- fallback path (round-1, device atomics) ----------------

__global__ void zero_kernel(float* __restrict__ p, int n) {
    int i = blockIdx.x * blockDim.x + threadIdx.x;
    int stride = gridDim.x * blockDim.x;
    for (; i < n; i += stride) p[i] = 0.0f;
}

__global__ __launch_bounds__(256) void hop_atomic(
    const int* __restrict__ src, const int* __restrict__ dst,
    const float* __restrict__ ew, const float* __restrict__ cur,
    float* __restrict__ nxt) {
    int e = blockIdx.x * blockDim.x + threadIdx.x;
    if (e * 4 < NEDGE) {
        int4   s = ((const int4*)src)[e];
        int4   d = ((const int4*)dst)[e];
        float4 w = ((const float4*)ew)[e];
        atomicAdd(&nxt[d.x], cur[s.x] * w.x);
        atomicAdd(&nxt[d.y], cur[s.y] * w.y);
        atomicAdd(&nxt[d.z], cur[s.z] * w.z);
        atomicAdd(&nxt[d.w], cur[s.w] * w.w);
    }
}

// ---------------- finalize: 5->64 matvec + BatchNorm over features ----------------

__global__ __launch_bounds__(256) void finalize_kernel(
    const float* __restrict__ x,  const float* __restrict__ f1,
    const float* __restrict__ f2, const float* __restrict__ f3,
    const float* __restrict__ f4, const float* __restrict__ W,
    const float* __restrict__ bias, const float* __restrict__ gamma,
    const float* __restrict__ beta, float* __restrict__ out) {
    int lane = threadIdx.x & 63;
    int waveInBlock = threadIdx.x >> 6;
    int wavesPerBlock = blockDim.x >> 6;
    int gwave  = blockIdx.x * wavesPerBlock + waveInBlock;
    int nwaves = gridDim.x * wavesPerBlock;

    float w0 = W[lane * 5 + 0];
    float w1 = W[lane * 5 + 1];
    float w2 = W[lane * 5 + 2];
    float w3 = W[lane * 5 + 3];
    float w4 = W[lane * 5 + 4];
    float b  = bias[lane];

    for (int n = gwave; n < N_USERS; n += nwaves) {
        float c0 = x[n], c1 = f1[n], c2 = f2[n], c3 = f3[n], c4 = f4[n];
        float y = b + c0 * w0 + c1 * w1 + c2 * w2 + c3 * w3 + c4 * w4;

        float s = y;
        #pragma unroll
        for (int off = 32; off; off >>= 1) s += __shfl_xor(s, off);
        float mean = s * (1.0f / 64.0f);

        float d = y - mean;
        float v = d * d;
        #pragma unroll
        for (int off = 32; off; off >>= 1) v += __shfl_xor(v, off);
        float var = v * (1.0f / 64.0f);

        float o = d * rsqrtf(var + BN_EPS) * gamma[n] + beta[n];
        __builtin_nontemporal_store(o, &out[(size_t)n * OUT_F + lane]);
    }
}

extern "C" void kernel_launch(void* const* d_in, const int* in_sizes, int n_in,
                              void* d_out, int out_size, void* d_ws, size_t ws_size,
                              hipStream_t stream) {
    const float* x     = (const float*)d_in[0];
    const int*   ei    = (const int*)d_in[1];
    const float* ew    = (const float*)d_in[2];
    const float* W     = (const float*)d_in[3];
    const float* bias  = (const float*)d_in[4];
    const float* gamma = (const float*)d_in[5];
    const float* beta  = (const float*)d_in[6];
    float* out = (float*)d_out;

    const int* src = ei;
    const int* dst = ei + NEDGE;

    // Workspace layout
    float* f = (float*)d_ws;                           // 4*N floats (16 MB)
    uint2* rec = (uint2*)(f + 4ull * N_USERS);         // NB*CAP records (273 MB)
    unsigned* cursors = (unsigned*)(rec + (size_t)NB * CAP);
    size_t needed = 4ull * N_USERS * 4 + (size_t)NB * CAP * 8 + (size_t)NB * 4;

    if (ws_size >= needed) {
        init_cursors<<<1, 256, 0, stream>>>(cursors);
        zero_kernel<<<2048, 256, 0, stream>>>(f, 4 * N_USERS);   // hop flush is atomicAdd
        scatter_bin<<<SCAT_BLOCKS, 256, 0, stream>>>(src, dst, ew, rec, cursors);
        const float* cur = x;
        for (int h = 0; h < 4; ++h) {
            float* nxt = f + (size_t)h * N_USERS;
            hop_bucket_split<<<NB * SPLIT, 256, 0, stream>>>(rec, cursors, cur, nxt);
            cur = nxt;
        }
    } else {
        zero_kernel<<<4096, 256, 0, stream>>>(f, 4 * N_USERS);
        const float* cur = x;
        for (int h = 0; h < 4; ++h) {
            float* nxt = f + (size_t)h * N_USERS;
            hop_atomic<<<NEDGE / 4 / 256, 256, 0, stream>>>(src, dst, ew, cur, nxt);
            cur = nxt;
        }
    }

    finalize_kernel<<<2048, 256, 0, stream>>>(
        x, f, f + N_USERS, f + 2 * N_USERS, f + 3 * N_USERS,
        W, bias, gamma, beta, out);
}